// Round 3
// baseline (1315.839 us; speedup 1.0000x reference)
//
#include <hip/hip_runtime.h>
#include <math.h>

#define N_NODES 50000
#define N_EDGES 1600000
#define IN_CH 32
#define HID 64

// ---------------- workspace layout (float/int element offsets into d_ws)
#define WS_DEG_OUT   0          // 50000 f  (becomes reciprocal after recip_kernel)
#define WS_DEG_IN    50000      // 50000 f
#define WS_CNT_COL   100000     // 50000 i
#define WS_CNT_ROW   150000     // 50000 i
#define WS_OFFS_COL  200000     // 50001 i (padded to 50004)
#define WS_OFFS_ROW  250004     // 50001 i (padded)
#define WS_CUR_COL   300008     // 50000 i
#define WS_CUR_ROW   350008     // 50000 i
#define WS_PAIR_COL  400008     // 3200000 i : int2 (src, coef_bits) per edge, col-sorted
#define WS_PAIR_ROW  3600008    // 3200000 i : int2 per edge, row-sorted
#define WS_TXO       6800008    // 1600000 f (50000 x 32)
#define WS_TXI       8400008    // 1600000 f
#define WS_TOTAL     10000008   // 40.0 MB

__global__ void zero_kernel(float4* __restrict__ p, int n4) {
    int i = blockIdx.x * blockDim.x + threadIdx.x;
    int stride = gridDim.x * blockDim.x;
    for (; i < n4; i += stride) p[i] = make_float4(0.f, 0.f, 0.f, 0.f);
}

// degrees + bucket counts: 4 atomics / edge
__global__ void deg_cnt_kernel(const int* __restrict__ ei, const float* __restrict__ ew,
                               float* __restrict__ deg_out, float* __restrict__ deg_in,
                               int* __restrict__ cnt_col, int* __restrict__ cnt_row) {
    int e = blockIdx.x * blockDim.x + threadIdx.x;
    if (e >= N_EDGES) return;
    int r = ei[e];
    int c = ei[N_EDGES + e];
    float w = ew[e];
    atomicAdd(&deg_out[r], w);
    atomicAdd(&deg_in[c], w);
    atomicAdd(&cnt_col[c], 1);
    atomicAdd(&cnt_row[r], 1);
}

__global__ void recip_kernel(float* __restrict__ deg, int n) {
    int i = blockIdx.x * blockDim.x + threadIdx.x;
    if (i >= n) return;
    float v = deg[i];
    deg[i] = (v != 0.f) ? (1.f / v) : 0.f;
}

// Exclusive scan of 50000 counts -> offs (+ total at offs[n]) + copy to cur.
__global__ __launch_bounds__(1024) void scan_kernel(int* __restrict__ ws_i) {
    const int n = N_NODES;
    const int T = 1024, CH = (n + T - 1) / T;  // 49
    __shared__ int s[1024];
    const int* cnt = ws_i + (blockIdx.x == 0 ? WS_CNT_COL : WS_CNT_ROW);
    int* offs = ws_i + (blockIdx.x == 0 ? WS_OFFS_COL : WS_OFFS_ROW);
    int* cur = ws_i + (blockIdx.x == 0 ? WS_CUR_COL : WS_CUR_ROW);

    int t = threadIdx.x;
    int beg = t * CH, end = min(beg + CH, n);
    int part = 0;
    for (int i = beg; i < end; ++i) part += cnt[i];
    s[t] = part;
    __syncthreads();
    for (int off = 1; off < T; off <<= 1) {
        int v = (t >= off) ? s[t - off] : 0;
        __syncthreads();
        s[t] += v;
        __syncthreads();
    }
    int prefix = s[t] - part;  // exclusive
    int run = prefix;
    for (int i = beg; i < end; ++i) {
        offs[i] = run;
        cur[i] = run;
        run += cnt[i];
    }
    if (t == T - 1) offs[n] = s[T - 1];
}

// bucket-sort edges by destination: one packed int2 (src, coef) store per edge per dir
__global__ void scatter_kernel(const int* __restrict__ ei, const float* __restrict__ ew,
                               const float* __restrict__ rdeg_out, const float* __restrict__ rdeg_in,
                               int* __restrict__ cur_col, int* __restrict__ cur_row,
                               int2* __restrict__ pair_col, int2* __restrict__ pair_row) {
    int e = blockIdx.x * blockDim.x + threadIdx.x;
    if (e >= N_EDGES) return;
    int r = ei[e];
    int c = ei[N_EDGES + e];
    float w = ew[e];
    float co = w * rdeg_out[r];  // forward:  w / deg_out[row], lands at node col
    float ci = w * rdeg_in[c];   // backward: w / deg_in[col],  lands at node row
    int p = atomicAdd(&cur_col[c], 1);
    pair_col[p] = make_int2(r, __float_as_int(co));
    int q = atomicAdd(&cur_row[r], 1);
    pair_row[q] = make_int2(c, __float_as_int(ci));
}

// register-accumulating gather: 8 lanes per node, one float4 of channels each.
#define GROUPS_PER_BLOCK 32
#define BLOCKS_PER_DIR ((N_NODES + GROUPS_PER_BLOCK - 1) / GROUPS_PER_BLOCK)  // 1563
__global__ __launch_bounds__(256) void gather_kernel(
    const float4* __restrict__ x4, const int* __restrict__ ws_i, float* __restrict__ ws_f) {
    int b = blockIdx.x;
    int dir = (b >= BLOCKS_PER_DIR) ? 1 : 0;
    int node = (b - dir * BLOCKS_PER_DIR) * GROUPS_PER_BLOCK + (threadIdx.x >> 3);
    if (node >= N_NODES) return;
    int lane = threadIdx.x & 7;

    const int* offs = ws_i + (dir == 0 ? WS_OFFS_COL : WS_OFFS_ROW);
    const int2* pair = (const int2*)(ws_i + (dir == 0 ? WS_PAIR_COL : WS_PAIR_ROW));
    float4* outp = (float4*)(ws_f + (dir == 0 ? WS_TXO : WS_TXI));

    int p = offs[node], end = offs[node + 1];
    float4 acc = make_float4(0.f, 0.f, 0.f, 0.f);
    for (; p + 1 < end; p += 2) {
        int2 e0 = pair[p], e1 = pair[p + 1];
        float c0 = __int_as_float(e0.y), c1 = __int_as_float(e1.y);
        float4 a = x4[e0.x * 8 + lane];
        float4 bb = x4[e1.x * 8 + lane];
        acc.x += c0 * a.x + c1 * bb.x;
        acc.y += c0 * a.y + c1 * bb.y;
        acc.z += c0 * a.z + c1 * bb.z;
        acc.w += c0 * a.w + c1 * bb.w;
    }
    if (p < end) {
        int2 e0 = pair[p];
        float c0 = __int_as_float(e0.y);
        float4 a = x4[e0.x * 8 + lane];
        acc.x += c0 * a.x;
        acc.y += c0 * a.y;
        acc.z += c0 * a.z;
        acc.w += c0 * a.w;
    }
    outp[node * 8 + lane] = acc;
}

// Fused dense epilogue, restructured:
//   - 512 persistent blocks, grid-stride over groups of 32 nodes
//   - weights staged to LDS ONCE per block (amortized over ~98 nodes)
//   - each wave batches 8 nodes in registers -> 8x LDS weight-read reuse
// Weight slab layout k = slab*32 + c: slab0 = W[0,0]+W[1,0] (identity term),
// slab1 = W[0,1] (Tx_o), slab2 = W[1,1] (Tx_i). W flat [d][kk][96][64].
#define DN_GROUP 32
#define DN_GROUPS ((N_NODES + DN_GROUP - 1) / DN_GROUP)  // 1563
#define DN_BLOCKS 512
__global__ __launch_bounds__(256) void dense_kernel(
    const float4* __restrict__ x4,
    const float4* __restrict__ txo4, const float4* __restrict__ txi4,
    const float* __restrict__ Wz, const float* __restrict__ bz,
    const float* __restrict__ Wh, const float* __restrict__ bh,
    const float* __restrict__ Wlin, const float* __restrict__ blin,
    float* __restrict__ out) {
    __shared__ float s_wz[96 * 64];      // 24 KB
    __shared__ float s_wh[96 * 64];      // 24 KB
    __shared__ float s_in[DN_GROUP * 96];  // 12 KB

    int tid = threadIdx.x;
    for (int idx = tid; idx < 96 * 64; idx += 256) {
        int k = idx >> 6, o = idx & 63;
        int slab = k >> 5, c = k & 31;
        float wz, wh;
        if (slab == 0) {
            wz = Wz[c * 64 + o] + Wz[(2 * 96 + c) * 64 + o];
            wh = Wh[c * 64 + o] + Wh[(2 * 96 + c) * 64 + o];
        } else if (slab == 1) {
            wz = Wz[(96 + c) * 64 + o];
            wh = Wh[(96 + c) * 64 + o];
        } else {
            wz = Wz[(3 * 96 + c) * 64 + o];
            wh = Wh[(3 * 96 + c) * 64 + o];
        }
        s_wz[idx] = wz;
        s_wh[idx] = wh;
    }
    int o = tid & 63, w = tid >> 6;
    float bzo = bz[o], bho = bh[o], wlo = Wlin[o], bl = blin[0];
    __syncthreads();

    for (int g = blockIdx.x; g < DN_GROUPS; g += DN_BLOCKS) {
        int node0 = g * DN_GROUP;
        // stage 32 nodes x 96 ch (768 float4; 3 per thread)
        for (int idx = tid; idx < DN_GROUP * 24; idx += 256) {
            int nl = idx / 24, q = idx - nl * 24;
            int node = node0 + nl;
            float4 v = make_float4(0.f, 0.f, 0.f, 0.f);
            if (node < N_NODES) {
                if (q < 8)       v = x4[node * 8 + q];
                else if (q < 16) v = txo4[node * 8 + (q - 8)];
                else             v = txi4[node * 8 + (q - 16)];
            }
            *(float4*)&s_in[nl * 96 + q * 4] = v;
        }
        __syncthreads();

        // wave w handles nodes [w*8, w*8+8) of this group; lane = output ch o
        float accz[8], acch[8];
#pragma unroll
        for (int n = 0; n < 8; ++n) { accz[n] = bzo; acch[n] = bho; }
        const float* base = &s_in[w * 8 * 96];
#pragma unroll
        for (int kq = 0; kq < 24; ++kq) {
            float4 xk[8];
#pragma unroll
            for (int n = 0; n < 8; ++n)
                xk[n] = *(const float4*)&base[n * 96 + kq * 4];  // broadcast read
            float wz0 = s_wz[(kq * 4 + 0) * 64 + o];
            float wz1 = s_wz[(kq * 4 + 1) * 64 + o];
            float wz2 = s_wz[(kq * 4 + 2) * 64 + o];
            float wz3 = s_wz[(kq * 4 + 3) * 64 + o];
            float wh0 = s_wh[(kq * 4 + 0) * 64 + o];
            float wh1 = s_wh[(kq * 4 + 1) * 64 + o];
            float wh2 = s_wh[(kq * 4 + 2) * 64 + o];
            float wh3 = s_wh[(kq * 4 + 3) * 64 + o];
#pragma unroll
            for (int n = 0; n < 8; ++n) {
                accz[n] += xk[n].x * wz0 + xk[n].y * wz1 + xk[n].z * wz2 + xk[n].w * wz3;
                acch[n] += xk[n].x * wh0 + xk[n].y * wh1 + xk[n].z * wh2 + xk[n].w * wh3;
            }
        }
        // epilogue: Z/H-tilde/GRU combine/ReLU/Wlin + 64-lane reduce
#pragma unroll
        for (int n = 0; n < 8; ++n) {
            float z = 1.f / (1.f + __expf(-accz[n]));
            float ht = tanhf(acch[n]);
            float rr = fmaxf((1.f - z) * ht, 0.f) * wlo;
#pragma unroll
            for (int off = 32; off > 0; off >>= 1)
                rr += __shfl_down(rr, off, 64);
            if (o == 0) {
                int node = node0 + w * 8 + n;
                if (node < N_NODES) out[node] = rr + bl;
            }
        }
        __syncthreads();  // protect s_in before next group's staging
    }
}

extern "C" void kernel_launch(void* const* d_in, const int* in_sizes, int n_in,
                              void* d_out, int out_size, void* d_ws, size_t ws_size,
                              hipStream_t stream) {
    const float* x = (const float*)d_in[0];
    const int* ei = (const int*)d_in[1];
    const float* ew = (const float*)d_in[2];
    const float* Wz = (const float*)d_in[3];
    const float* bz = (const float*)d_in[4];
    // d_in[5]=Wr, d_in[6]=br dead: H0==0 makes the reset gate a no-op
    const float* Wh = (const float*)d_in[7];
    const float* bh = (const float*)d_in[8];
    const float* Wlin = (const float*)d_in[9];
    const float* blin = (const float*)d_in[10];
    float* out = (float*)d_out;
    float* wf = (float*)d_ws;
    int* wi = (int*)d_ws;

    // 1. zero degrees + counts; pair/Tx buffers are fully overwritten later
    zero_kernel<<<196, 256, 0, stream>>>((float4*)wf, 200000 / 4);
    // 2. degrees + bucket counts
    deg_cnt_kernel<<<(N_EDGES + 255) / 256, 256, 0, stream>>>(
        ei, ew, wf + WS_DEG_OUT, wf + WS_DEG_IN, wi + WS_CNT_COL, wi + WS_CNT_ROW);
    // 3. reciprocal degrees in place
    recip_kernel<<<(2 * N_NODES + 255) / 256, 256, 0, stream>>>(wf + WS_DEG_OUT, 2 * N_NODES);
    // 4. counts -> offsets (+cur) for both orderings
    scan_kernel<<<2, 1024, 0, stream>>>(wi);
    // 5. bucket-sort edges (packed int2) by destination node, per direction
    scatter_kernel<<<(N_EDGES + 255) / 256, 256, 0, stream>>>(
        ei, ew, wf + WS_DEG_OUT, wf + WS_DEG_IN, wi + WS_CUR_COL, wi + WS_CUR_ROW,
        (int2*)(wi + WS_PAIR_COL), (int2*)(wi + WS_PAIR_ROW));
    // 6. atomic-free register-accumulating gather -> Tx_o, Tx_i
    gather_kernel<<<2 * BLOCKS_PER_DIR, 256, 0, stream>>>((const float4*)x, wi, wf);
    // 7. fused dense epilogue (persistent blocks, weights staged once per block)
    dense_kernel<<<DN_BLOCKS, 256, 0, stream>>>(
        (const float4*)x, (const float4*)(wf + WS_TXO), (const float4*)(wf + WS_TXI),
        Wz, bz, Wh, bh, Wlin, blin, out);
}

// Round 4
// 795.966 us; speedup vs baseline: 1.6531x; 1.6531x over previous
//
#include <hip/hip_runtime.h>
#include <math.h>

#define N_NODES 50000
#define N_EDGES 1600000
#define IN_CH 32
#define HID 64

// ---------------- workspace layout (float/int element offsets into d_ws)
#define WS_DEG_OUT   0          // 50000 f  (becomes reciprocal after recip_kernel)
#define WS_DEG_IN    50000      // 50000 f
#define WS_CNT_COL   100000     // 50000 i
#define WS_CNT_ROW   150000     // 50000 i
#define WS_OFFS_COL  200000     // 50001 i (padded to 50004)
#define WS_OFFS_ROW  250004     // 50001 i (padded)
#define WS_CUR_COL   300008     // 50000 i
#define WS_CUR_ROW   350008     // 50000 i
#define WS_PAIR_COL  400008     // 3200000 i : int2 (src, coef_bits) per edge, col-sorted
#define WS_PAIR_ROW  3600008    // 3200000 i : int2 per edge, row-sorted
#define WS_TXO       6800008    // 1600000 f (50000 x 32)
#define WS_TXI       8400008    // 1600000 f
#define WS_TOTAL     10000008   // 40.0 MB

__global__ void zero_kernel(float4* __restrict__ p, int n4) {
    int i = blockIdx.x * blockDim.x + threadIdx.x;
    int stride = gridDim.x * blockDim.x;
    for (; i < n4; i += stride) p[i] = make_float4(0.f, 0.f, 0.f, 0.f);
}

// degrees + bucket counts: 4 atomics / edge
__global__ void deg_cnt_kernel(const int* __restrict__ ei, const float* __restrict__ ew,
                               float* __restrict__ deg_out, float* __restrict__ deg_in,
                               int* __restrict__ cnt_col, int* __restrict__ cnt_row) {
    int e = blockIdx.x * blockDim.x + threadIdx.x;
    if (e >= N_EDGES) return;
    int r = ei[e];
    int c = ei[N_EDGES + e];
    float w = ew[e];
    atomicAdd(&deg_out[r], w);
    atomicAdd(&deg_in[c], w);
    atomicAdd(&cnt_col[c], 1);
    atomicAdd(&cnt_row[r], 1);
}

__global__ void recip_kernel(float* __restrict__ deg, int n) {
    int i = blockIdx.x * blockDim.x + threadIdx.x;
    if (i >= n) return;
    float v = deg[i];
    deg[i] = (v != 0.f) ? (1.f / v) : 0.f;
}

// Exclusive scan of 50000 counts -> offs (+ total at offs[n]) + copy to cur.
__global__ __launch_bounds__(1024) void scan_kernel(int* __restrict__ ws_i) {
    const int n = N_NODES;
    const int T = 1024, CH = (n + T - 1) / T;  // 49
    __shared__ int s[1024];
    const int* cnt = ws_i + (blockIdx.x == 0 ? WS_CNT_COL : WS_CNT_ROW);
    int* offs = ws_i + (blockIdx.x == 0 ? WS_OFFS_COL : WS_OFFS_ROW);
    int* cur = ws_i + (blockIdx.x == 0 ? WS_CUR_COL : WS_CUR_ROW);

    int t = threadIdx.x;
    int beg = t * CH, end = min(beg + CH, n);
    int part = 0;
    for (int i = beg; i < end; ++i) part += cnt[i];
    s[t] = part;
    __syncthreads();
    for (int off = 1; off < T; off <<= 1) {
        int v = (t >= off) ? s[t - off] : 0;
        __syncthreads();
        s[t] += v;
        __syncthreads();
    }
    int prefix = s[t] - part;  // exclusive
    int run = prefix;
    for (int i = beg; i < end; ++i) {
        offs[i] = run;
        cur[i] = run;
        run += cnt[i];
    }
    if (t == T - 1) offs[n] = s[T - 1];
}

// bucket-sort edges by destination: one packed int2 (src, coef) store per edge per dir
__global__ void scatter_kernel(const int* __restrict__ ei, const float* __restrict__ ew,
                               const float* __restrict__ rdeg_out, const float* __restrict__ rdeg_in,
                               int* __restrict__ cur_col, int* __restrict__ cur_row,
                               int2* __restrict__ pair_col, int2* __restrict__ pair_row) {
    int e = blockIdx.x * blockDim.x + threadIdx.x;
    if (e >= N_EDGES) return;
    int r = ei[e];
    int c = ei[N_EDGES + e];
    float w = ew[e];
    float co = w * rdeg_out[r];  // forward:  w / deg_out[row], lands at node col
    float ci = w * rdeg_in[c];   // backward: w / deg_in[col],  lands at node row
    int p = atomicAdd(&cur_col[c], 1);
    pair_col[p] = make_int2(r, __float_as_int(co));
    int q = atomicAdd(&cur_row[r], 1);
    pair_row[q] = make_int2(c, __float_as_int(ci));
}

// register-accumulating gather: 8 lanes per node, one float4 of channels each.
#define GROUPS_PER_BLOCK 32
#define BLOCKS_PER_DIR ((N_NODES + GROUPS_PER_BLOCK - 1) / GROUPS_PER_BLOCK)  // 1563
__global__ __launch_bounds__(256) void gather_kernel(
    const float4* __restrict__ x4, const int* __restrict__ ws_i, float* __restrict__ ws_f) {
    int b = blockIdx.x;
    int dir = (b >= BLOCKS_PER_DIR) ? 1 : 0;
    int node = (b - dir * BLOCKS_PER_DIR) * GROUPS_PER_BLOCK + (threadIdx.x >> 3);
    if (node >= N_NODES) return;
    int lane = threadIdx.x & 7;

    const int* offs = ws_i + (dir == 0 ? WS_OFFS_COL : WS_OFFS_ROW);
    const int2* pair = (const int2*)(ws_i + (dir == 0 ? WS_PAIR_COL : WS_PAIR_ROW));
    float4* outp = (float4*)(ws_f + (dir == 0 ? WS_TXO : WS_TXI));

    int p = offs[node], end = offs[node + 1];
    float4 acc = make_float4(0.f, 0.f, 0.f, 0.f);
    for (; p + 1 < end; p += 2) {
        int2 e0 = pair[p], e1 = pair[p + 1];
        float c0 = __int_as_float(e0.y), c1 = __int_as_float(e1.y);
        float4 a = x4[e0.x * 8 + lane];
        float4 bb = x4[e1.x * 8 + lane];
        acc.x += c0 * a.x + c1 * bb.x;
        acc.y += c0 * a.y + c1 * bb.y;
        acc.z += c0 * a.z + c1 * bb.z;
        acc.w += c0 * a.w + c1 * bb.w;
    }
    if (p < end) {
        int2 e0 = pair[p];
        float c0 = __int_as_float(e0.y);
        float4 a = x4[e0.x * 8 + lane];
        acc.x += c0 * a.x;
        acc.y += c0 * a.y;
        acc.z += c0 * a.z;
        acc.w += c0 * a.w;
    }
    outp[node * 8 + lane] = acc;
}

// Fused dense epilogue v3:
//   - 782 blocks, one group of 64 nodes each (no persistence; weight staging is
//     ~1.1k LDS-write cycles per block, negligible)
//   - weights TRANSPOSED in LDS: s_w{z,h}T[o][k], stride 100 floats (400 B ->
//     16B-aligned float4 reads; lane-to-lane offset 100 -> uniform bank spread)
//   - each wave batches 16 nodes: accz[16]/acch[16] in regs (32 VGPR), one
//     input float4 in flight (NO xk[] array -- round 3's 256-VGPR spill fix)
//   - per kq: 2 weight b128 + 16 input b128 (broadcast) feed 256 VALU cycles
// Weight slab layout k = slab*32 + c: slab0 = W[0,0]+W[1,0] (identity term),
// slab1 = W[0,1] (Tx_o), slab2 = W[1,1] (Tx_i). W flat [d][kk][96][64].
#define DN_GROUP 64
#define DN_BLOCKS ((N_NODES + DN_GROUP - 1) / DN_GROUP)  // 782
#define WT_STRIDE 100
__global__ __launch_bounds__(256) void dense_kernel(
    const float4* __restrict__ x4,
    const float4* __restrict__ txo4, const float4* __restrict__ txi4,
    const float* __restrict__ Wz, const float* __restrict__ bz,
    const float* __restrict__ Wh, const float* __restrict__ bh,
    const float* __restrict__ Wlin, const float* __restrict__ blin,
    float* __restrict__ out) {
    __shared__ float s_wzT[64 * WT_STRIDE];  // 25.6 KB
    __shared__ float s_whT[64 * WT_STRIDE];  // 25.6 KB
    __shared__ float s_in[DN_GROUP * 96];    // 24.0 KB   (total 75.2 KB -> 2 blocks/CU)

    int tid = threadIdx.x;
    int o = tid & 63, w = tid >> 6;
    float bzo = bz[o], bho = bh[o], wlo = Wlin[o], bl = blin[0];

    // stage weights, transposed to [o][k]
    for (int idx = tid; idx < 96 * 64; idx += 256) {
        int k = idx >> 6, oo = idx & 63;
        int slab = k >> 5, c = k & 31;
        float wz, wh;
        if (slab == 0) {
            wz = Wz[c * 64 + oo] + Wz[(2 * 96 + c) * 64 + oo];
            wh = Wh[c * 64 + oo] + Wh[(2 * 96 + c) * 64 + oo];
        } else if (slab == 1) {
            wz = Wz[(96 + c) * 64 + oo];
            wh = Wh[(96 + c) * 64 + oo];
        } else {
            wz = Wz[(3 * 96 + c) * 64 + oo];
            wh = Wh[(3 * 96 + c) * 64 + oo];
        }
        s_wzT[oo * WT_STRIDE + k] = wz;
        s_whT[oo * WT_STRIDE + k] = wh;
    }

    // stage 64 nodes x 96 ch (1536 float4; 6 per thread)
    int node0 = blockIdx.x * DN_GROUP;
    for (int idx = tid; idx < DN_GROUP * 24; idx += 256) {
        int nl = idx / 24, q = idx - nl * 24;
        int node = node0 + nl;
        float4 v = make_float4(0.f, 0.f, 0.f, 0.f);
        if (node < N_NODES) {
            if (q < 8)       v = x4[node * 8 + q];
            else if (q < 16) v = txo4[node * 8 + (q - 8)];
            else             v = txi4[node * 8 + (q - 16)];
        }
        *(float4*)&s_in[nl * 96 + q * 4] = v;
    }
    __syncthreads();

    // wave w handles nodes [w*16, w*16+16); lane = output ch o
    float accz[16], acch[16];
#pragma unroll
    for (int n = 0; n < 16; ++n) { accz[n] = bzo; acch[n] = bho; }
    const float* wzp = &s_wzT[o * WT_STRIDE];
    const float* whp = &s_whT[o * WT_STRIDE];
    const float* inp = &s_in[w * 16 * 96];

    for (int kq = 0; kq < 24; ++kq) {  // rolled: ~1.2 KB body, I-cache friendly
        float4 wz = *(const float4*)&wzp[kq * 4];
        float4 wh = *(const float4*)&whp[kq * 4];
#pragma unroll
        for (int n = 0; n < 16; ++n) {
            float4 xk = *(const float4*)&inp[n * 96 + kq * 4];  // broadcast read
            accz[n] += xk.x * wz.x + xk.y * wz.y + xk.z * wz.z + xk.w * wz.w;
            acch[n] += xk.x * wh.x + xk.y * wh.y + xk.z * wh.z + xk.w * wh.w;
        }
    }

    // epilogue: Z / H-tilde / (1-Z)*Ht / ReLU / *Wlin + 64-lane reduce
#pragma unroll
    for (int n = 0; n < 16; ++n) {
        float z = 1.f / (1.f + __expf(-accz[n]));
        float ht = 1.f - 2.f / (__expf(2.f * acch[n]) + 1.f);  // tanh, safe at +-inf
        float rr = fmaxf((1.f - z) * ht, 0.f) * wlo;
#pragma unroll
        for (int off = 32; off > 0; off >>= 1)
            rr += __shfl_down(rr, off, 64);
        if (o == 0) {
            int node = node0 + w * 16 + n;
            if (node < N_NODES) out[node] = rr + bl;
        }
    }
}

extern "C" void kernel_launch(void* const* d_in, const int* in_sizes, int n_in,
                              void* d_out, int out_size, void* d_ws, size_t ws_size,
                              hipStream_t stream) {
    const float* x = (const float*)d_in[0];
    const int* ei = (const int*)d_in[1];
    const float* ew = (const float*)d_in[2];
    const float* Wz = (const float*)d_in[3];
    const float* bz = (const float*)d_in[4];
    // d_in[5]=Wr, d_in[6]=br dead: H0==0 makes the reset gate a no-op
    const float* Wh = (const float*)d_in[7];
    const float* bh = (const float*)d_in[8];
    const float* Wlin = (const float*)d_in[9];
    const float* blin = (const float*)d_in[10];
    float* out = (float*)d_out;
    float* wf = (float*)d_ws;
    int* wi = (int*)d_ws;

    // 1. zero degrees + counts; pair/Tx buffers are fully overwritten later
    zero_kernel<<<196, 256, 0, stream>>>((float4*)wf, 200000 / 4);
    // 2. degrees + bucket counts
    deg_cnt_kernel<<<(N_EDGES + 255) / 256, 256, 0, stream>>>(
        ei, ew, wf + WS_DEG_OUT, wf + WS_DEG_IN, wi + WS_CNT_COL, wi + WS_CNT_ROW);
    // 3. reciprocal degrees in place
    recip_kernel<<<(2 * N_NODES + 255) / 256, 256, 0, stream>>>(wf + WS_DEG_OUT, 2 * N_NODES);
    // 4. counts -> offsets (+cur) for both orderings
    scan_kernel<<<2, 1024, 0, stream>>>(wi);
    // 5. bucket-sort edges (packed int2) by destination node, per direction
    scatter_kernel<<<(N_EDGES + 255) / 256, 256, 0, stream>>>(
        ei, ew, wf + WS_DEG_OUT, wf + WS_DEG_IN, wi + WS_CUR_COL, wi + WS_CUR_ROW,
        (int2*)(wi + WS_PAIR_COL), (int2*)(wi + WS_PAIR_ROW));
    // 6. atomic-free register-accumulating gather -> Tx_o, Tx_i
    gather_kernel<<<2 * BLOCKS_PER_DIR, 256, 0, stream>>>((const float4*)x, wi, wf);
    // 7. fused dense epilogue (weights transposed in LDS, 16-node register batch)
    dense_kernel<<<DN_BLOCKS, 256, 0, stream>>>(
        (const float4*)x, (const float4*)(wf + WS_TXO), (const float4*)(wf + WS_TXI),
        Wz, bz, Wh, bh, Wlin, blin, out);
}